// Round 2
// baseline (1291.169 us; speedup 1.0000x reference)
//
#include <hip/hip_runtime.h>
#include <cstdint>

// Problem constants (B,S,D,H) = (8,1024,1024,16), HD=64
#define NB 8
#define NS 1024
#define ND 1024
#define NH 16
#define HD 64
static constexpr float LN_EPS = 1e-5f;

typedef unsigned short u16;
typedef short s16x8 __attribute__((ext_vector_type(8)));
typedef short s16x4 __attribute__((ext_vector_type(4)));
typedef float fx4   __attribute__((ext_vector_type(4)));

// float -> bf16 bits, round-to-nearest-even
__device__ __forceinline__ u16 f2bf(float f) {
  union { float f; unsigned u; } v; v.f = f;
  return (u16)((v.u + 0x7fffu + ((v.u >> 16) & 1u)) >> 16);
}

// ---- async global->LDS, 16B per lane (wave-uniform LDS base + lane*16) ----
__device__ __forceinline__ void gl_lds16(const void* g, void* lds) {
  __builtin_amdgcn_global_load_lds(
      (const __attribute__((address_space(1))) void*)g,
      (__attribute__((address_space(3))) void*)lds, 16, 0, 0);
}

// ---------------- f32 -> bf16 convert (vectorized) ----------------
__global__ __launch_bounds__(256) void cvt_f32_bf16(const float* __restrict__ in,
                                                    u16* __restrict__ out, int n4) {
  for (int i = blockIdx.x * 256 + threadIdx.x; i < n4; i += gridDim.x * 256) {
    const float4 v = reinterpret_cast<const float4*>(in)[i];
    s16x4 o;
    o[0] = (short)f2bf(v.x); o[1] = (short)f2bf(v.y);
    o[2] = (short)f2bf(v.z); o[3] = (short)f2bf(v.w);
    reinterpret_cast<s16x4*>(out)[i] = o;
  }
}

// ---------------- generic bt-layout GEMM: C[M,N] = A[M,K] @ B[N,K]^T ----------------
// 128x128 tile, BK=32, 4 waves (2x2), 16x16x32 bf16 MFMA, double-buffered LDS,
// global_load_lds staging. All dims multiples of 128 (K multiple of 32).
enum { EPI_SCORES = 0, EPI_QKV = 1, EPI_BIASRES = 2, EPI_FF1 = 3 };

template <int EPI>
__global__ __launch_bounds__(256, 2) void gemm_bt(
    const u16* __restrict__ A, const u16* __restrict__ B,
    const float* __restrict__ bias, const float* __restrict__ res,
    float* __restrict__ outF, u16* __restrict__ outB,
    u16* __restrict__ outQ, u16* __restrict__ outK, u16* __restrict__ outV,
    int M, int N, int K, long zsA, long zsB, long zsC) {
  __shared__ u16 sA[2][128 * 32];
  __shared__ u16 sB[2][128 * 32];
  const int t = threadIdx.x;
  const int lane = t & 63, wid = t >> 6;
  const int wm = wid >> 1, wn = wid & 1;
  const int z = blockIdx.z;
  A += (long)z * zsA;
  B += (long)z * zsB;
  const int tm0 = blockIdx.y * 128, tn0 = blockIdx.x * 128;
  const int nk = K >> 5;

  fx4 acc[4][4];
  const fx4 vzero = {0.f, 0.f, 0.f, 0.f};
#pragma unroll
  for (int i = 0; i < 4; ++i)
#pragma unroll
    for (int j = 0; j < 4; ++j) acc[i][j] = vzero;

  auto stage = [&](int buf, int kt) {
    const int k0 = kt << 5;
#pragma unroll
    for (int i = 0; i < 2; ++i) {
      const int e = (i * 256 + t) * 8;
      const int row = e >> 5, col = e & 31;
      gl_lds16(A + (long)(tm0 + row) * K + k0 + col, &sA[buf][e]);
    }
#pragma unroll
    for (int i = 0; i < 2; ++i) {
      const int e = (i * 256 + t) * 8;
      const int row = e >> 5, col = e & 31;
      gl_lds16(B + (long)(tn0 + row) * K + k0 + col, &sB[buf][e]);
    }
  };

  stage(0, 0);
  for (int kt = 0; kt < nk; ++kt) {
    const int cur = kt & 1;
    __syncthreads();  // drains vmcnt (stage into cur complete), protects buf reuse
    if (kt + 1 < nk) stage(cur ^ 1, kt + 1);
    const int ar = wm * 64 + (lane & 15);
    const int br = wn * 64 + (lane & 15);
    const int kc = (lane >> 4) * 8;
    s16x8 a[4], b[4];
#pragma unroll
    for (int i = 0; i < 4; ++i) a[i] = *(const s16x8*)&sA[cur][(ar + i * 16) * 32 + kc];
#pragma unroll
    for (int i = 0; i < 4; ++i) b[i] = *(const s16x8*)&sB[cur][(br + i * 16) * 32 + kc];
#pragma unroll
    for (int mi = 0; mi < 4; ++mi)
#pragma unroll
      for (int ni = 0; ni < 4; ++ni)
        acc[mi][ni] = __builtin_amdgcn_mfma_f32_16x16x32_bf16(a[mi], b[ni], acc[mi][ni], 0, 0, 0);
  }

#pragma unroll
  for (int mi = 0; mi < 4; ++mi) {
#pragma unroll
    for (int ni = 0; ni < 4; ++ni) {
#pragma unroll
      for (int r = 0; r < 4; ++r) {
        const int row = tm0 + wm * 64 + mi * 16 + (lane >> 4) * 4 + r;
        const int col = tn0 + wn * 64 + ni * 16 + (lane & 15);
        float v = acc[mi][ni][r];
        if constexpr (EPI == EPI_SCORES) {
          outF[(long)z * zsC + (long)row * N + col] = v;
        } else if constexpr (EPI == EPI_QKV) {
          v += bias[col];
          const int bb = row >> 10, s = row & 1023;
          const int h = (col >> 6) & 15, d = col & 63;
          if (col < 1024)
            outQ[(((long)bb * NH + h) * NS + s) * HD + d] = f2bf(v * 0.125f);
          else if (col < 2048)
            outK[(((long)bb * NH + h) * NS + s) * HD + d] = f2bf(v);
          else
            outV[(((long)bb * NH + h) * HD + d) * NS + s] = f2bf(v);  // V transposed
        } else if constexpr (EPI == EPI_BIASRES) {
          v += bias[col] + res[(long)row * N + col];
          outF[(long)row * N + col] = v;
        } else {  // EPI_FF1: bias + relu -> bf16
          v += bias[col];
          v = v > 0.f ? v : 0.f;
          outB[(long)row * N + col] = f2bf(v);
        }
      }
    }
  }
}

// ---------------- PV GEMM: ctx[q,d] = sum_k P[q,k] * V[k,d], per (b,h) ----------------
// A = probs fp32 [1024,1024] (converted to bf16 during LDS staging), B = V^T [64,1024] bf16.
// Tile 128(M) x 64(N), BK=32, 4 waves each 32 rows.
__global__ __launch_bounds__(256, 2) void pv_gemm(const float* __restrict__ P,
                                                  const u16* __restrict__ Vt,
                                                  u16* __restrict__ ctxb) {
  __shared__ u16 sP[2][128 * 32];
  __shared__ u16 sV[2][64 * 32];
  const int t = threadIdx.x, lane = t & 63, w = t >> 6;
  const int z = blockIdx.y, bb = z >> 4, h = z & 15;
  const float* Pz = P + (long)z * (NS * NS);
  const u16* Vz = Vt + (long)z * (HD * NS);
  const int tm0 = blockIdx.x * 128;

  fx4 acc[2][4];
  const fx4 vzero = {0.f, 0.f, 0.f, 0.f};
#pragma unroll
  for (int i = 0; i < 2; ++i)
#pragma unroll
    for (int j = 0; j < 4; ++j) acc[i][j] = vzero;

  auto stage = [&](int buf, int kt) {
    const int k0 = kt << 5;
#pragma unroll
    for (int i = 0; i < 4; ++i) {
      const int e4 = (i * 256 + t) * 4;
      const int row = e4 >> 5, col = e4 & 31;
      const float4 v = *(const float4*)&Pz[(long)(tm0 + row) * NS + k0 + col];
      s16x4 o;
      o[0] = (short)f2bf(v.x); o[1] = (short)f2bf(v.y);
      o[2] = (short)f2bf(v.z); o[3] = (short)f2bf(v.w);
      *(s16x4*)&sP[buf][row * 32 + col] = o;
    }
    {
      const int e = t * 8;
      const int row = e >> 5, col = e & 31;
      gl_lds16(Vz + (long)row * NS + k0 + col, &sV[buf][e]);
    }
  };

  stage(0, 0);
  for (int kt = 0; kt < 32; ++kt) {
    const int cur = kt & 1;
    __syncthreads();
    if (kt + 1 < 32) stage(cur ^ 1, kt + 1);
    const int ar = w * 32 + (lane & 15);
    const int kc = (lane >> 4) * 8;
    s16x8 a[2], b[4];
#pragma unroll
    for (int i = 0; i < 2; ++i) a[i] = *(const s16x8*)&sP[cur][(ar + i * 16) * 32 + kc];
#pragma unroll
    for (int i = 0; i < 4; ++i) b[i] = *(const s16x8*)&sV[cur][(i * 16 + (lane & 15)) * 32 + kc];
#pragma unroll
    for (int mi = 0; mi < 2; ++mi)
#pragma unroll
      for (int ni = 0; ni < 4; ++ni)
        acc[mi][ni] = __builtin_amdgcn_mfma_f32_16x16x32_bf16(a[mi], b[ni], acc[mi][ni], 0, 0, 0);
  }

#pragma unroll
  for (int mi = 0; mi < 2; ++mi)
#pragma unroll
    for (int ni = 0; ni < 4; ++ni)
#pragma unroll
      for (int r = 0; r < 4; ++r) {
        const int row = tm0 + w * 32 + mi * 16 + (lane >> 4) * 4 + r;
        const int col = ni * 16 + (lane & 15);
        ctxb[((long)bb * NS + row) * ND + h * HD + col] = f2bf(acc[mi][ni][r]);
      }
}

// ---------------- row softmax in-place, one block per row (1024 cols) ----------------
__global__ __launch_bounds__(256) void softmax_rows(float* __restrict__ P) {
  float* p = P + (long)blockIdx.x * 1024;
  const int t = threadIdx.x, lane = t & 63, w = t >> 6;
  __shared__ float red[4];
  float4 v = *(float4*)&p[t * 4];
  float m = fmaxf(fmaxf(v.x, v.y), fmaxf(v.z, v.w));
#pragma unroll
  for (int o = 32; o >= 1; o >>= 1) m = fmaxf(m, __shfl_xor(m, o));
  if (lane == 0) red[w] = m;
  __syncthreads();
  m = fmaxf(fmaxf(red[0], red[1]), fmaxf(red[2], red[3]));
  v.x = __expf(v.x - m); v.y = __expf(v.y - m);
  v.z = __expf(v.z - m); v.w = __expf(v.w - m);
  float s = v.x + v.y + v.z + v.w;
#pragma unroll
  for (int o = 32; o >= 1; o >>= 1) s += __shfl_xor(s, o);
  __syncthreads();  // red reuse
  if (lane == 0) red[w] = s;
  __syncthreads();
  s = red[0] + red[1] + red[2] + red[3];
  const float inv = 1.0f / s;
  v.x *= inv; v.y *= inv; v.z *= inv; v.w *= inv;
  *(float4*)&p[t * 4] = v;
}

// ---------------- layernorm rows (1024 cols), optional bf16 copy ----------------
__global__ __launch_bounds__(256) void ln_rows(const float* __restrict__ Y,
                                               const float* __restrict__ g,
                                               const float* __restrict__ beta,
                                               float* __restrict__ outF,
                                               u16* __restrict__ outB) {
  const long row = blockIdx.x;
  const float* y = Y + row * 1024;
  const int t = threadIdx.x, lane = t & 63, w = t >> 6;
  __shared__ float rs_[4], rq_[4];
  const float4 v = *(const float4*)&y[t * 4];
  float s = v.x + v.y + v.z + v.w;
  float q = v.x * v.x + v.y * v.y + v.z * v.z + v.w * v.w;
#pragma unroll
  for (int o = 32; o >= 1; o >>= 1) { s += __shfl_xor(s, o); q += __shfl_xor(q, o); }
  if (lane == 0) { rs_[w] = s; rq_[w] = q; }
  __syncthreads();
  s = rs_[0] + rs_[1] + rs_[2] + rs_[3];
  q = rq_[0] + rq_[1] + rq_[2] + rq_[3];
  const float mean = s * (1.f / 1024.f);
  const float var = q * (1.f / 1024.f) - mean * mean;
  const float inv = rsqrtf(var + LN_EPS);
  const float4 gg = *(const float4*)&g[t * 4];
  const float4 bb = *(const float4*)&beta[t * 4];
  float o0 = (v.x - mean) * inv * gg.x + bb.x;
  float o1 = (v.y - mean) * inv * gg.y + bb.y;
  float o2 = (v.z - mean) * inv * gg.z + bb.z;
  float o3 = (v.w - mean) * inv * gg.w + bb.w;
  float4 ov; ov.x = o0; ov.y = o1; ov.z = o2; ov.w = o3;
  *(float4*)&outF[row * 1024 + t * 4] = ov;
  if (outB != nullptr) {
    s16x4 ob;
    ob[0] = (short)f2bf(o0); ob[1] = (short)f2bf(o1);
    ob[2] = (short)f2bf(o2); ob[3] = (short)f2bf(o3);
    *(s16x4*)&outB[row * 1024 + t * 4] = ob;
  }
}

extern "C" void kernel_launch(void* const* d_in, const int* in_sizes, int n_in,
                              void* d_out, int out_size, void* d_ws, size_t ws_size,
                              hipStream_t stream) {
  const float* x    = (const float*)d_in[0];
  const float* Wqkv = (const float*)d_in[1];
  const float* bqkv = (const float*)d_in[2];
  const float* Wout = (const float*)d_in[3];
  const float* bout = (const float*)d_in[4];
  const float* W1   = (const float*)d_in[5];
  const float* b1   = (const float*)d_in[6];
  const float* W2   = (const float*)d_in[7];
  const float* b2   = (const float*)d_in[8];
  const float* g1   = (const float*)d_in[9];
  const float* be1  = (const float*)d_in[10];
  const float* g2   = (const float*)d_in[11];
  const float* be2  = (const float*)d_in[12];

  float* x2    = (float*)d_out;
  float* probs = (float*)d_out + (long)NB * NS * ND;  // [B,H,S,S]

  char* ws = (char*)d_ws;
  size_t off = 0;
  auto alloc = [&](size_t bytes) -> void* {
    void* p = ws + off;
    off += (bytes + 255) & ~(size_t)255;
    return p;
  };
  u16* xb   = (u16*)alloc((size_t)8192 * 1024 * 2);
  u16* wqb  = (u16*)alloc((size_t)3072 * 1024 * 2);
  u16* wob  = (u16*)alloc((size_t)1024 * 1024 * 2);
  u16* w1b  = (u16*)alloc((size_t)2048 * 1024 * 2);
  u16* w2b  = (u16*)alloc((size_t)1024 * 2048 * 2);
  u16* qb   = (u16*)alloc((size_t)NB * NH * NS * HD * 2);
  u16* kb   = (u16*)alloc((size_t)NB * NH * NS * HD * 2);
  u16* vb   = (u16*)alloc((size_t)NB * NH * HD * NS * 2);  // transposed per head
  u16* ctxb = (u16*)alloc((size_t)8192 * 1024 * 2);
  float* yres = (float*)alloc((size_t)8192 * 1024 * 4);  // residual sums (both)
  float* x1f  = (float*)alloc((size_t)8192 * 1024 * 4);
  u16* x1b  = (u16*)alloc((size_t)8192 * 1024 * 2);
  u16* h1b  = (u16*)alloc((size_t)8192 * 2048 * 2);

  // 1) convert inputs to bf16
  cvt_f32_bf16<<<2048, 256, 0, stream>>>(x, xb, 8192 * 1024 / 4);
  cvt_f32_bf16<<<2048, 256, 0, stream>>>(Wqkv, wqb, 3072 * 1024 / 4);
  cvt_f32_bf16<<<512, 256, 0, stream>>>(Wout, wob, 1024 * 1024 / 4);
  cvt_f32_bf16<<<1024, 256, 0, stream>>>(W1, w1b, 2048 * 1024 / 4);
  cvt_f32_bf16<<<1024, 256, 0, stream>>>(W2, w2b, 1024 * 2048 / 4);

  // 2) QKV projection, split epilogue (q scaled by 1/sqrt(64))
  gemm_bt<EPI_QKV><<<dim3(24, 64, 1), 256, 0, stream>>>(
      xb, wqb, bqkv, nullptr, nullptr, nullptr, qb, kb, vb, 8192, 3072, 1024, 0, 0, 0);

  // 3) scores = q @ k^T per (b,h), fp32 into probs buffer
  gemm_bt<EPI_SCORES><<<dim3(8, 8, 128), 256, 0, stream>>>(
      qb, kb, nullptr, nullptr, probs, nullptr, nullptr, nullptr, nullptr,
      1024, 1024, 64, (long)NS * HD, (long)NS * HD, (long)NS * NS);

  // 4) softmax rows in-place -> final probs output
  softmax_rows<<<NB * NH * NS, 256, 0, stream>>>(probs);

  // 5) ctx = probs @ v
  pv_gemm<<<dim3(8, 128), 256, 0, stream>>>(probs, vb, ctxb);

  // 6) attn_out = ctx @ Wout^T + bout; + residual x -> yres (fp32)
  gemm_bt<EPI_BIASRES><<<dim3(8, 64, 1), 256, 0, stream>>>(
      ctxb, wob, bout, x, yres, nullptr, nullptr, nullptr, nullptr, 8192, 1024, 1024, 0, 0, 0);

  // 7) x1 = LN(yres)
  ln_rows<<<8192, 256, 0, stream>>>(yres, g1, be1, x1f, x1b);

  // 8) h1 = relu(x1 @ W1^T + b1)
  gemm_bt<EPI_FF1><<<dim3(16, 64, 1), 256, 0, stream>>>(
      x1b, w1b, b1, nullptr, nullptr, h1b, nullptr, nullptr, nullptr, 8192, 2048, 1024, 0, 0, 0);

  // 9) ff = h1 @ W2^T + b2; + residual x1 -> yres
  gemm_bt<EPI_BIASRES><<<dim3(8, 64, 1), 256, 0, stream>>>(
      h1b, w2b, b2, x1f, yres, nullptr, nullptr, nullptr, nullptr, 8192, 1024, 2048, 0, 0, 0);

  // 10) x2 = LN(yres)
  ln_rows<<<8192, 256, 0, stream>>>(yres, g2, be2, x2, nullptr);
}

// Round 3
// 1185.645 us; speedup vs baseline: 1.0890x; 1.0890x over previous
//
#include <hip/hip_runtime.h>
#include <cstdint>

// Problem constants (B,S,D,H) = (8,1024,1024,16), HD=64
#define NB 8
#define NS 1024
#define ND 1024
#define NH 16
#define HD 64
static constexpr float LN_EPS = 1e-5f;

typedef unsigned short u16;
typedef short s16x8 __attribute__((ext_vector_type(8)));
typedef short s16x4 __attribute__((ext_vector_type(4)));
typedef float fx4   __attribute__((ext_vector_type(4)));

// float -> bf16 bits, round-to-nearest-even
__device__ __forceinline__ u16 f2bf(float f) {
  union { float f; unsigned u; } v; v.f = f;
  return (u16)((v.u + 0x7fffu + ((v.u >> 16) & 1u)) >> 16);
}

// ---- async global->LDS, 16B per lane (wave-uniform LDS base + lane*16) ----
__device__ __forceinline__ void gl_lds16(const void* g, void* lds) {
  __builtin_amdgcn_global_load_lds(
      (const __attribute__((address_space(1))) void*)g,
      (__attribute__((address_space(3))) void*)lds, 16, 0, 0);
}

// ---------------- fused f32 -> bf16 convert for all 5 tensors ----------------
__global__ __launch_bounds__(256) void cvt_all(
    const float* __restrict__ s0, u16* __restrict__ d0, int n0,
    const float* __restrict__ s1, u16* __restrict__ d1, int n1,
    const float* __restrict__ s2, u16* __restrict__ d2, int n2,
    const float* __restrict__ s3, u16* __restrict__ d3, int n3,
    const float* __restrict__ s4, u16* __restrict__ d4, int n4) {
  const int c0 = n0, c1 = c0 + n1, c2 = c1 + n2, c3 = c2 + n3, c4 = c3 + n4;
  for (int i = blockIdx.x * 256 + threadIdx.x; i < c4; i += gridDim.x * 256) {
    const float* s; u16* d; int j;
    if (i < c0)      { s = s0; d = d0; j = i; }
    else if (i < c1) { s = s1; d = d1; j = i - c0; }
    else if (i < c2) { s = s2; d = d2; j = i - c1; }
    else if (i < c3) { s = s3; d = d3; j = i - c2; }
    else             { s = s4; d = d4; j = i - c3; }
    const float4 v = reinterpret_cast<const float4*>(s)[j];
    s16x4 o;
    o[0] = (short)f2bf(v.x); o[1] = (short)f2bf(v.y);
    o[2] = (short)f2bf(v.z); o[3] = (short)f2bf(v.w);
    reinterpret_cast<s16x4*>(d)[j] = o;
  }
}

// ---------------- generic bt-layout GEMM: C[M,N] = A[M,K] @ B[N,K]^T ----------------
enum { EPI_QKV = 1, EPI_BIASRES = 2, EPI_FF1 = 3 };

template <int EPI>
__global__ __launch_bounds__(256, 2) void gemm_bt(
    const u16* __restrict__ A, const u16* __restrict__ B,
    const float* __restrict__ bias, const float* __restrict__ res,
    float* __restrict__ outF, u16* __restrict__ outB,
    u16* __restrict__ outQ, u16* __restrict__ outK, u16* __restrict__ outV,
    int M, int N, int K) {
  __shared__ u16 sA[2][128 * 32];
  __shared__ u16 sB[2][128 * 32];
  const int t = threadIdx.x;
  const int lane = t & 63, wid = t >> 6;
  const int wm = wid >> 1, wn = wid & 1;
  const int tm0 = blockIdx.y * 128, tn0 = blockIdx.x * 128;
  const int nk = K >> 5;

  fx4 acc[4][4];
  const fx4 vzero = {0.f, 0.f, 0.f, 0.f};
#pragma unroll
  for (int i = 0; i < 4; ++i)
#pragma unroll
    for (int j = 0; j < 4; ++j) acc[i][j] = vzero;

  auto stage = [&](int buf, int kt) {
    const int k0 = kt << 5;
#pragma unroll
    for (int i = 0; i < 2; ++i) {
      const int e = (i * 256 + t) * 8;
      const int row = e >> 5, col = e & 31;
      gl_lds16(A + (long)(tm0 + row) * K + k0 + col, &sA[buf][e]);
    }
#pragma unroll
    for (int i = 0; i < 2; ++i) {
      const int e = (i * 256 + t) * 8;
      const int row = e >> 5, col = e & 31;
      gl_lds16(B + (long)(tn0 + row) * K + k0 + col, &sB[buf][e]);
    }
  };

  stage(0, 0);
  for (int kt = 0; kt < nk; ++kt) {
    const int cur = kt & 1;
    __syncthreads();
    if (kt + 1 < nk) stage(cur ^ 1, kt + 1);
    const int ar = wm * 64 + (lane & 15);
    const int br = wn * 64 + (lane & 15);
    const int kc = (lane >> 4) * 8;
    s16x8 a[4], b[4];
#pragma unroll
    for (int i = 0; i < 4; ++i) a[i] = *(const s16x8*)&sA[cur][(ar + i * 16) * 32 + kc];
#pragma unroll
    for (int i = 0; i < 4; ++i) b[i] = *(const s16x8*)&sB[cur][(br + i * 16) * 32 + kc];
#pragma unroll
    for (int mi = 0; mi < 4; ++mi)
#pragma unroll
      for (int ni = 0; ni < 4; ++ni)
        acc[mi][ni] = __builtin_amdgcn_mfma_f32_16x16x32_bf16(a[mi], b[ni], acc[mi][ni], 0, 0, 0);
  }

#pragma unroll
  for (int mi = 0; mi < 4; ++mi) {
#pragma unroll
    for (int ni = 0; ni < 4; ++ni) {
#pragma unroll
      for (int r = 0; r < 4; ++r) {
        const int row = tm0 + wm * 64 + mi * 16 + (lane >> 4) * 4 + r;
        const int col = tn0 + wn * 64 + ni * 16 + (lane & 15);
        float v = acc[mi][ni][r];
        if constexpr (EPI == EPI_QKV) {
          v += bias[col];
          const int bb = row >> 10, s = row & 1023;
          const int h = (col >> 6) & 15, d = col & 63;
          if (col < 1024)
            outQ[(((long)bb * NH + h) * NS + s) * HD + d] = f2bf(v * 0.125f);
          else if (col < 2048)
            outK[(((long)bb * NH + h) * NS + s) * HD + d] = f2bf(v);
          else
            outV[(((long)bb * NH + h) * HD + d) * NS + s] = f2bf(v);  // V transposed
        } else if constexpr (EPI == EPI_BIASRES) {
          v += bias[col] + res[(long)row * N + col];
          outF[(long)row * N + col] = v;
        } else {  // EPI_FF1: bias + relu -> bf16
          v += bias[col];
          v = v > 0.f ? v : 0.f;
          outB[(long)row * N + col] = f2bf(v);
        }
      }
    }
  }
}

// ---------------- fused attention: S = qK^T, softmax (-> probs fp32), ctx = P V ----------------
// Per block: one (b,h) z-slice, 16 query rows. 4 waves.
// Loop 1 over 16 key-tiles of 64: S strip [16 x 1024] in registers (wave w owns
// cols kt*64 + w*16 + 0..15 of each tile). Wave-parallel softmax via shfl + LDS.
// P written fp32 to probs (output) and bf16 to swizzled LDS; loop 2 computes PV.
// All LDS tiles XOR-swizzled (byte ^= (row&7)<<4) against D-stride bank pathology;
// global_load_lds sources are pre-swizzled to match (both-sides rule).
__global__ __launch_bounds__(256, 2) void attn_fused(
    const u16* __restrict__ qb, const u16* __restrict__ kb, const u16* __restrict__ vb,
    float* __restrict__ probs, u16* __restrict__ ctxb) {
  __shared__ u16 sK[2][64 * 64];   // [key][k]  8 KB each
  __shared__ u16 sV[2][64 * 64];   // [d][kp]   8 KB each
  __shared__ u16 sP[16 * 1024];    // [qrow][key] 32 KB
  __shared__ float redA[16][4], redB[16][4];
  const int t = threadIdx.x, l = t & 63, w = t >> 6;
  const int g = l >> 4, m = l & 15;
  const int z = blockIdx.y;
  const int q0 = blockIdx.x * 16;
  const int bb = z >> 4, h = z & 15;
  const u16* Qz = qb + (long)z * (NS * HD);
  const u16* Kz = kb + (long)z * (NS * HD);
  const u16* Vz = vb + (long)z * (HD * NS);

  // Q fragments in registers (A-frag: row = lane&15, k = 8*(lane>>4)+j)
  s16x8 qf[2];
#pragma unroll
  for (int kk = 0; kk < 2; ++kk)
    qf[kk] = *(const s16x8*)&Qz[(q0 + m) * HD + kk * 32 + g * 8];

  auto stageK = [&](int buf, int kt) {
#pragma unroll
    for (int i = 0; i < 2; ++i) {
      const int a = (i * 256 + t) * 16;  // LDS byte within tile
      const int row = a >> 7, off = a & 127;
      const int soff = off ^ ((row & 7) << 4);  // pre-swizzled source
      gl_lds16(Kz + (kt * 64 + row) * HD + (soff >> 1), (char*)&sK[buf][0] + a);
    }
  };
  auto stageV = [&](int buf, int kt) {
#pragma unroll
    for (int i = 0; i < 2; ++i) {
      const int a = (i * 256 + t) * 16;
      const int row = a >> 7, off = a & 127;  // row = d
      const int soff = off ^ ((row & 7) << 4);
      gl_lds16(Vz + (long)row * NS + kt * 64 + (soff >> 1), (char*)&sV[buf][0] + a);
    }
  };

  // ---- loop 1: S = (q/8) K^T ----
  fx4 sacc[16];
  const fx4 vzero = {0.f, 0.f, 0.f, 0.f};
#pragma unroll
  for (int i = 0; i < 16; ++i) sacc[i] = vzero;

  stageK(0, 0);
  for (int kt = 0; kt < 16; ++kt) {
    const int cur = kt & 1;
    __syncthreads();
    if (kt + 1 < 16) stageK(cur ^ 1, kt + 1);
    const int krow = w * 16 + m;  // B-frag row = lane&15 within wave's 16-key tile
#pragma unroll
    for (int kk = 0; kk < 2; ++kk) {
      const s16x8 bf = *(const s16x8*)((const char*)&sK[cur][0] + krow * 128 +
                                       ((kk * 64 + g * 16) ^ ((krow & 7) << 4)));
      sacc[kt] = __builtin_amdgcn_mfma_f32_16x16x32_bf16(qf[kk], bf, sacc[kt], 0, 0, 0);
    }
  }

  // ---- softmax over full rows (qrow = 4g+r; key col of sacc[i] = i*64 + w*16 + m) ----
  float rmax[4], rsum[4];
#pragma unroll
  for (int r = 0; r < 4; ++r) {
    float mx = sacc[0][r];
#pragma unroll
    for (int i = 1; i < 16; ++i) mx = fmaxf(mx, sacc[i][r]);
    mx = fmaxf(mx, __shfl_xor(mx, 1));
    mx = fmaxf(mx, __shfl_xor(mx, 2));
    mx = fmaxf(mx, __shfl_xor(mx, 4));
    mx = fmaxf(mx, __shfl_xor(mx, 8));
    rmax[r] = mx;
  }
  if (m == 0) {
#pragma unroll
    for (int r = 0; r < 4; ++r) redA[4 * g + r][w] = rmax[r];
  }
  __syncthreads();
#pragma unroll
  for (int r = 0; r < 4; ++r) {
    const float* rr = redA[4 * g + r];
    rmax[r] = fmaxf(fmaxf(rr[0], rr[1]), fmaxf(rr[2], rr[3]));
    rsum[r] = 0.f;
  }
#pragma unroll
  for (int i = 0; i < 16; ++i)
#pragma unroll
    for (int r = 0; r < 4; ++r) {
      const float e = __expf(sacc[i][r] - rmax[r]);
      sacc[i][r] = e;
      rsum[r] += e;
    }
#pragma unroll
  for (int r = 0; r < 4; ++r) {
    float s = rsum[r];
    s += __shfl_xor(s, 1); s += __shfl_xor(s, 2);
    s += __shfl_xor(s, 4); s += __shfl_xor(s, 8);
    rsum[r] = s;
  }
  if (m == 0) {
#pragma unroll
    for (int r = 0; r < 4; ++r) redB[4 * g + r][w] = rsum[r];
  }
  __syncthreads();
  float inv[4];
#pragma unroll
  for (int r = 0; r < 4; ++r) {
    const float* rr = redB[4 * g + r];
    inv[r] = 1.0f / (rr[0] + rr[1] + rr[2] + rr[3]);
  }

  // ---- write P: fp32 to global (output), bf16 to swizzled LDS ----
  float* Pz = probs + (long)z * (NS * NS);
#pragma unroll
  for (int i = 0; i < 16; ++i) {
    const int col = i * 64 + w * 16 + m;
#pragma unroll
    for (int r = 0; r < 4; ++r) {
      const int qr = 4 * g + r;
      const float p = sacc[i][r] * inv[r];
      Pz[(long)(q0 + qr) * NS + col] = p;
      *(u16*)((char*)sP + qr * 2048 + ((col * 2) ^ ((qr & 7) << 4))) = f2bf(p);
    }
  }

  // ---- loop 2: ctx = P V (wave w computes d-slice w*16..+16) ----
  fx4 cacc = vzero;
  stageV(0, 0);
  for (int kt = 0; kt < 16; ++kt) {
    const int cur = kt & 1;
    __syncthreads();  // kt=0: makes sP visible + drains stageV(0,0)
    if (kt + 1 < 16) stageV(cur ^ 1, kt + 1);
    const int d = w * 16 + m;
#pragma unroll
    for (int kk = 0; kk < 2; ++kk) {
      const s16x8 af = *(const s16x8*)((const char*)sP + m * 2048 +
                                       ((kt * 128 + kk * 64 + g * 16) ^ ((m & 7) << 4)));
      const s16x8 bf = *(const s16x8*)((const char*)&sV[cur][0] + d * 128 +
                                       ((kk * 64 + g * 16) ^ ((d & 7) << 4)));
      cacc = __builtin_amdgcn_mfma_f32_16x16x32_bf16(af, bf, cacc, 0, 0, 0);
    }
  }
#pragma unroll
  for (int r = 0; r < 4; ++r) {
    const int qr = 4 * g + r;
    ctxb[((long)bb * NS + q0 + qr) * ND + h * HD + w * 16 + m] = f2bf(cacc[r]);
  }
}

// ---------------- layernorm rows (1024 cols), optional bf16 copy ----------------
__global__ __launch_bounds__(256) void ln_rows(const float* __restrict__ Y,
                                               const float* __restrict__ g,
                                               const float* __restrict__ beta,
                                               float* __restrict__ outF,
                                               u16* __restrict__ outB) {
  const long row = blockIdx.x;
  const float* y = Y + row * 1024;
  const int t = threadIdx.x, lane = t & 63, w = t >> 6;
  __shared__ float rs_[4], rq_[4];
  const float4 v = *(const float4*)&y[t * 4];
  float s = v.x + v.y + v.z + v.w;
  float q = v.x * v.x + v.y * v.y + v.z * v.z + v.w * v.w;
#pragma unroll
  for (int o = 32; o >= 1; o >>= 1) { s += __shfl_xor(s, o); q += __shfl_xor(q, o); }
  if (lane == 0) { rs_[w] = s; rq_[w] = q; }
  __syncthreads();
  s = rs_[0] + rs_[1] + rs_[2] + rs_[3];
  q = rq_[0] + rq_[1] + rq_[2] + rq_[3];
  const float mean = s * (1.f / 1024.f);
  const float var = q * (1.f / 1024.f) - mean * mean;
  const float inv = rsqrtf(var + LN_EPS);
  const float4 gg = *(const float4*)&g[t * 4];
  const float4 bb = *(const float4*)&beta[t * 4];
  float o0 = (v.x - mean) * inv * gg.x + bb.x;
  float o1 = (v.y - mean) * inv * gg.y + bb.y;
  float o2 = (v.z - mean) * inv * gg.z + bb.z;
  float o3 = (v.w - mean) * inv * gg.w + bb.w;
  float4 ov; ov.x = o0; ov.y = o1; ov.z = o2; ov.w = o3;
  *(float4*)&outF[row * 1024 + t * 4] = ov;
  if (outB != nullptr) {
    s16x4 ob;
    ob[0] = (short)f2bf(o0); ob[1] = (short)f2bf(o1);
    ob[2] = (short)f2bf(o2); ob[3] = (short)f2bf(o3);
    *(s16x4*)&outB[row * 1024 + t * 4] = ob;
  }
}

extern "C" void kernel_launch(void* const* d_in, const int* in_sizes, int n_in,
                              void* d_out, int out_size, void* d_ws, size_t ws_size,
                              hipStream_t stream) {
  const float* x    = (const float*)d_in[0];
  const float* Wqkv = (const float*)d_in[1];
  const float* bqkv = (const float*)d_in[2];
  const float* Wout = (const float*)d_in[3];
  const float* bout = (const float*)d_in[4];
  const float* W1   = (const float*)d_in[5];
  const float* b1   = (const float*)d_in[6];
  const float* W2   = (const float*)d_in[7];
  const float* b2   = (const float*)d_in[8];
  const float* g1   = (const float*)d_in[9];
  const float* be1  = (const float*)d_in[10];
  const float* g2   = (const float*)d_in[11];
  const float* be2  = (const float*)d_in[12];

  float* x2    = (float*)d_out;
  float* probs = (float*)d_out + (long)NB * NS * ND;  // [B,H,S,S]

  char* ws = (char*)d_ws;
  size_t off = 0;
  auto alloc = [&](size_t bytes) -> void* {
    void* p = ws + off;
    off += (bytes + 255) & ~(size_t)255;
    return p;
  };
  u16* xb   = (u16*)alloc((size_t)8192 * 1024 * 2);
  u16* wqb  = (u16*)alloc((size_t)3072 * 1024 * 2);
  u16* wob  = (u16*)alloc((size_t)1024 * 1024 * 2);
  u16* w1b  = (u16*)alloc((size_t)2048 * 1024 * 2);
  u16* w2b  = (u16*)alloc((size_t)1024 * 2048 * 2);
  u16* qb   = (u16*)alloc((size_t)NB * NH * NS * HD * 2);
  u16* kb   = (u16*)alloc((size_t)NB * NH * NS * HD * 2);
  u16* vb   = (u16*)alloc((size_t)NB * NH * HD * NS * 2);  // transposed per head
  u16* ctxb = (u16*)alloc((size_t)8192 * 1024 * 2);
  float* yres = (float*)alloc((size_t)8192 * 1024 * 4);
  float* x1f  = (float*)alloc((size_t)8192 * 1024 * 4);
  u16* x1b  = (u16*)alloc((size_t)8192 * 1024 * 2);
  u16* h1b  = (u16*)alloc((size_t)8192 * 2048 * 2);

  // 1) convert all fp32 inputs to bf16 (single kernel)
  cvt_all<<<2048, 256, 0, stream>>>(x, xb, 8192 * 1024 / 4,
                                    Wqkv, wqb, 3072 * 1024 / 4,
                                    Wout, wob, 1024 * 1024 / 4,
                                    W1, w1b, 2048 * 1024 / 4,
                                    W2, w2b, 2048 * 1024 / 4);

  // 2) QKV projection, split epilogue (q scaled by 1/sqrt(64))
  gemm_bt<EPI_QKV><<<dim3(24, 64), 256, 0, stream>>>(
      xb, wqb, bqkv, nullptr, nullptr, nullptr, qb, kb, vb, 8192, 3072, 1024);

  // 3) fused attention: scores + softmax (probs out) + PV
  attn_fused<<<dim3(64, 128), 256, 0, stream>>>(qb, kb, vb, probs, ctxb);

  // 4) attn_out = ctx @ Wout^T + bout; + residual x -> yres (fp32)
  gemm_bt<EPI_BIASRES><<<dim3(8, 64), 256, 0, stream>>>(
      ctxb, wob, bout, x, yres, nullptr, nullptr, nullptr, nullptr, 8192, 1024, 1024);

  // 5) x1 = LN(yres)
  ln_rows<<<8192, 256, 0, stream>>>(yres, g1, be1, x1f, x1b);

  // 6) h1 = relu(x1 @ W1^T + b1)
  gemm_bt<EPI_FF1><<<dim3(16, 64), 256, 0, stream>>>(
      x1b, w1b, b1, nullptr, nullptr, h1b, nullptr, nullptr, nullptr, 8192, 2048, 1024);

  // 7) ff = h1 @ W2^T + b2; + residual x1 -> yres
  gemm_bt<EPI_BIASRES><<<dim3(8, 64), 256, 0, stream>>>(
      h1b, w2b, b2, x1f, yres, nullptr, nullptr, nullptr, nullptr, 8192, 1024, 2048);

  // 8) x2 = LN(yres)
  ln_rows<<<8192, 256, 0, stream>>>(yres, g2, be2, x2, nullptr);
}